// Round 1
// baseline (426.785 us; speedup 1.0000x reference)
//
#include <hip/hip_runtime.h>

// Problem constants (from reference): B=8, C=3, T=16, H=W=224, P0=2, P=16, FC=2
#define Bd 8
#define Cd 3
#define Td 16
#define Hd 224
#define Wd 224
#define Nd 1568            // (T/2)*(H/16)*(W/16) = 8*14*14
#define Dd 1024            // 2*16*16*2
#define HWd (Hd*Wd)        // 50176
#define PATCH_ELEMS 1536.0 // p0*p1*p2*C = 2*16*16*3

// ---------------- mask count ----------------
__global__ void mask_count_kernel(const int* __restrict__ mask, int n,
                                  unsigned int* __restrict__ cnt) {
    int i = blockIdx.x * blockDim.x + threadIdx.x;
    int v = 0;
    int stride = gridDim.x * blockDim.x;
    for (; i < n; i += stride) v += (mask[i] != 0) ? 1 : 0;
    // wave-64 reduce
    for (int off = 32; off > 0; off >>= 1) v += __shfl_down(v, off, 64);
    __shared__ int sdata[4];
    int lane = threadIdx.x & 63, wid = threadIdx.x >> 6;
    if (lane == 0) sdata[wid] = v;
    __syncthreads();
    if (threadIdx.x == 0) {
        int s = sdata[0] + sdata[1] + sdata[2] + sdata[3];
        atomicAdd(cnt, (unsigned int)s);
    }
}

// ---------------- main fused kernel ----------------
// grid: (HWd/256 = 196, B*T = 128), block: 256
__global__ void flow_mse_kernel(const float* __restrict__ outp,   // (B,N,D)
                                const float* __restrict__ raw,    // (B,C,T,H,W)
                                const int* __restrict__ mask,     // (B,N)
                                double* __restrict__ gsum) {
    int pix = blockIdx.x * blockDim.x + threadIdx.x;  // 0..50175
    int bt  = blockIdx.y;
    int b = bt >> 4;
    int t = bt & 15;
    int h = pix / Wd;
    int w = pix - h * Wd;

    int n = (t >> 1) * 196 + (h >> 4) * 14 + (w >> 4);

    float acc = 0.f;
    if (mask[b * Nd + n] != 0) {
        // flow element: d = ((i0*16+i1)*16+i2)*2 + c, i0=t&1, i1=h&15, i2=w&15
        size_t fbase = ((size_t)b * Nd + n) * Dd
                     + ((((t & 1) << 4) + (h & 15)) << 5)
                     + ((w & 15) << 1);
        float fx = outp[fbase];
        float fy = outp[fbase + 1];
        float mx = fx + (float)w;
        float my = fy + (float)h;

        float x0 = floorf(mx), y0 = floorf(my);
        float wx = mx - x0,    wy = my - y0;
        int x0i = (int)x0, y0i = (int)y0;
        int x1i = x0i + 1, y1i = y0i + 1;

        bool vx0 = (x0i >= 0) && (x0i < Wd);
        bool vx1 = (x1i >= 0) && (x1i < Wd);
        bool vy0 = (y0i >= 0) && (y0i < Hd);
        bool vy1 = (y1i >= 0) && (y1i < Hd);

        int xc0 = min(max(x0i, 0), Wd - 1);
        int xc1 = min(max(x1i, 0), Wd - 1);
        int yc0 = min(max(y0i, 0), Hd - 1);
        int yc1 = min(max(y1i, 0), Hd - 1);

        float w00 = (1.f - wx) * (1.f - wy) * ((vx0 && vy0) ? 1.f : 0.f);
        float w01 = wx         * (1.f - wy) * ((vx1 && vy0) ? 1.f : 0.f);
        float w10 = (1.f - wx) * wy         * ((vx0 && vy1) ? 1.f : 0.f);
        float w11 = wx         * wy         * ((vx1 && vy1) ? 1.f : 0.f);

        int i00 = yc0 * Wd + xc0;
        int i01 = yc0 * Wd + xc1;
        int i10 = yc1 * Wd + xc0;
        int i11 = yc1 * Wd + xc1;

        #pragma unroll
        for (int c = 0; c < Cd; ++c) {
            const float* img = raw + (((size_t)b * Cd + c) * Td + t) * HWd;
            float v00 = img[i00];
            float v01 = img[i01];
            float v10 = img[i10];
            float v11 = img[i11];
            float rec = v00 * w00 + v01 * w01 + v10 * w10 + v11 * w11;
            float tgt = img[h * Wd + w];
            float d = rec - tgt;
            acc += d * d;
        }
    }

    // block reduce (4 waves of 64)
    for (int off = 32; off > 0; off >>= 1) acc += __shfl_down(acc, off, 64);
    __shared__ float sdata[4];
    int lane = threadIdx.x & 63, wid = threadIdx.x >> 6;
    if (lane == 0) sdata[wid] = acc;
    __syncthreads();
    if (threadIdx.x == 0) {
        float s = sdata[0] + sdata[1] + sdata[2] + sdata[3];
        atomicAdd(gsum, (double)s);
    }
}

// ---------------- finalize ----------------
__global__ void finalize_kernel(const double* __restrict__ gsum,
                                const unsigned int* __restrict__ cnt,
                                float* __restrict__ out) {
    if (threadIdx.x == 0 && blockIdx.x == 0) {
        unsigned int c = *cnt;
        double denom = (double)(c > 0u ? c : 1u) * PATCH_ELEMS;
        out[0] = (float)(gsum[0] / denom);
    }
}

extern "C" void kernel_launch(void* const* d_in, const int* in_sizes, int n_in,
                              void* d_out, int out_size, void* d_ws, size_t ws_size,
                              hipStream_t stream) {
    const float* outp = (const float*)d_in[0];   // (B,N,D) fp32
    const float* raw  = (const float*)d_in[1];   // (B,C,T,H,W) fp32
    const int*   mask = (const int*)d_in[2];     // (B,N) int (0/1)
    float* out = (float*)d_out;

    double*       gsum = (double*)d_ws;
    unsigned int* cnt  = (unsigned int*)((char*)d_ws + 8);

    // ws is poisoned 0xAA before each call — zero the accumulators.
    hipMemsetAsync(d_ws, 0, 16, stream);

    mask_count_kernel<<<49, 256, 0, stream>>>(mask, in_sizes[2], cnt);

    flow_mse_kernel<<<dim3(HWd / 256, Bd * Td), 256, 0, stream>>>(outp, raw, mask, gsum);

    finalize_kernel<<<1, 64, 0, stream>>>(gsum, cnt, out);
}

// Round 2
// 191.654 us; speedup vs baseline: 2.2269x; 2.2269x over previous
//
#include <hip/hip_runtime.h>

// Problem constants: B=8, C=3, T=16, H=W=224, P0=2, P=16, FC=2
#define Bd 8
#define Cd 3
#define Td 16
#define Hd 224
#define Wd 224
#define Nd 1568            // (T/2)*(H/16)*(W/16)
#define Dd 1024            // 2*16*16*2
#define HWd (Hd*Wd)        // 50176
#define TOTAL_PIX (Bd*Td*HWd)   // 6,422,528
#define MASK_N (Bd*Nd)          // 12544
#define PATCH_ELEMS 1536.0
#define NBLK 2048

// ---------------- main fused kernel: grid-stride partial reduction ----------
__global__ void flow_mse_partial(const float* __restrict__ outp,   // (B,N,D)
                                 const float* __restrict__ raw,    // (B,C,T,H,W)
                                 const int* __restrict__ mask,     // (B,N)
                                 float* __restrict__ partial) {    // (NBLK)
    const int stride = gridDim.x * blockDim.x;
    float acc = 0.f;

    for (int g = blockIdx.x * blockDim.x + threadIdx.x; g < TOTAL_PIX; g += stride) {
        int bt  = g / HWd;            // magic-mul, constant divisor
        int pix = g - bt * HWd;
        int b = bt >> 4;
        int t = bt & 15;
        int h = pix / Wd;
        int w = pix - h * Wd;

        int n = (t >> 1) * 196 + (h >> 4) * 14 + (w >> 4);

        if (mask[b * Nd + n] != 0) {
            size_t fbase = ((size_t)b * Nd + n) * Dd
                         + ((((t & 1) << 4) + (h & 15)) << 5)
                         + ((w & 15) << 1);
            float fx = outp[fbase];
            float fy = outp[fbase + 1];
            float mx = fx + (float)w;
            float my = fy + (float)h;

            float x0 = floorf(mx), y0 = floorf(my);
            float wx = mx - x0,    wy = my - y0;
            int x0i = (int)x0, y0i = (int)y0;
            int x1i = x0i + 1, y1i = y0i + 1;

            bool vx0 = (x0i >= 0) && (x0i < Wd);
            bool vx1 = (x1i >= 0) && (x1i < Wd);
            bool vy0 = (y0i >= 0) && (y0i < Hd);
            bool vy1 = (y1i >= 0) && (y1i < Hd);

            int xc0 = min(max(x0i, 0), Wd - 1);
            int xc1 = min(max(x1i, 0), Wd - 1);
            int yc0 = min(max(y0i, 0), Hd - 1);
            int yc1 = min(max(y1i, 0), Hd - 1);

            float w00 = (1.f - wx) * (1.f - wy) * ((vx0 && vy0) ? 1.f : 0.f);
            float w01 = wx         * (1.f - wy) * ((vx1 && vy0) ? 1.f : 0.f);
            float w10 = (1.f - wx) * wy         * ((vx0 && vy1) ? 1.f : 0.f);
            float w11 = wx         * wy         * ((vx1 && vy1) ? 1.f : 0.f);

            int i00 = yc0 * Wd + xc0;
            int i01 = yc0 * Wd + xc1;
            int i10 = yc1 * Wd + xc0;
            int i11 = yc1 * Wd + xc1;

            #pragma unroll
            for (int c = 0; c < Cd; ++c) {
                const float* img = raw + (((size_t)b * Cd + c) * Td + t) * HWd;
                float v00 = img[i00];
                float v01 = img[i01];
                float v10 = img[i10];
                float v11 = img[i11];
                float rec = v00 * w00 + v01 * w01 + v10 * w10 + v11 * w11;
                float tgt = img[h * Wd + w];
                float d = rec - tgt;
                acc += d * d;
            }
        }
    }

    // block reduce: 4 waves of 64
    for (int off = 32; off > 0; off >>= 1) acc += __shfl_down(acc, off, 64);
    __shared__ float sdata[4];
    int lane = threadIdx.x & 63, wid = threadIdx.x >> 6;
    if (lane == 0) sdata[wid] = acc;
    __syncthreads();
    if (threadIdx.x == 0) {
        partial[blockIdx.x] = sdata[0] + sdata[1] + sdata[2] + sdata[3];
    }
}

// ---------------- finalize: reduce partials + mask count ----------------
__global__ void finalize_kernel(const float* __restrict__ partial,
                                const int* __restrict__ mask,
                                float* __restrict__ out) {
    double s = 0.0;
    for (int i = threadIdx.x; i < NBLK; i += blockDim.x)
        s += (double)partial[i];
    int cnt = 0;
    for (int i = threadIdx.x; i < MASK_N; i += blockDim.x)
        cnt += (mask[i] != 0) ? 1 : 0;

    for (int off = 32; off > 0; off >>= 1) {
        s   += __shfl_down(s, off, 64);
        cnt += __shfl_down(cnt, off, 64);
    }
    __shared__ double sdat[4];
    __shared__ int    cdat[4];
    int lane = threadIdx.x & 63, wid = threadIdx.x >> 6;
    if (lane == 0) { sdat[wid] = s; cdat[wid] = cnt; }
    __syncthreads();
    if (threadIdx.x == 0) {
        double st = sdat[0] + sdat[1] + sdat[2] + sdat[3];
        int ct = cdat[0] + cdat[1] + cdat[2] + cdat[3];
        double denom = (double)(ct > 0 ? ct : 1) * PATCH_ELEMS;
        out[0] = (float)(st / denom);
    }
}

extern "C" void kernel_launch(void* const* d_in, const int* in_sizes, int n_in,
                              void* d_out, int out_size, void* d_ws, size_t ws_size,
                              hipStream_t stream) {
    const float* outp = (const float*)d_in[0];   // (B,N,D) fp32
    const float* raw  = (const float*)d_in[1];   // (B,C,T,H,W) fp32
    const int*   mask = (const int*)d_in[2];     // (B,N)
    float* out = (float*)d_out;

    float* partial = (float*)d_ws;               // NBLK floats, all written

    flow_mse_partial<<<NBLK, 256, 0, stream>>>(outp, raw, mask, partial);
    finalize_kernel<<<1, 256, 0, stream>>>(partial, mask, out);
}

// Round 3
// 184.638 us; speedup vs baseline: 2.3115x; 1.0380x over previous
//
#include <hip/hip_runtime.h>

// Problem constants: B=8, C=3, T=16, H=W=224, P0=2, P=16, FC=2
#define Bd 8
#define Cd 3
#define Td 16
#define Hd 224
#define Wd 224
#define Nd 1568            // (T/2)*(H/16)*(W/16)
#define Dd 1024            // 2*16*16*2
#define HWd (Hd*Wd)        // 50176
#define MASK_N (Bd*Nd)     // 12544 — also the number of blocks / partials
#define PATCH_ELEMS 1536.0

// ---------------- main fused kernel: one block per token --------------------
// grid = 12544 (B*N), block = 256. Each block handles one 2x16x16 token:
// thread = (i1,i2) spatial, loops i0 = 0,1 (the two frames).
// Mask check is block-uniform -> unmasked tokens retire immediately.
__global__ void flow_mse_tok(const float* __restrict__ outp,   // (B,N,D)
                             const float* __restrict__ raw,    // (B,C,T,H,W)
                             const int* __restrict__ mask,     // (B,N)
                             float* __restrict__ partial) {    // (MASK_N)
    const int tk = blockIdx.x;            // b*Nd + n
    const int tid = threadIdx.x;

    if (mask[tk] == 0) {                  // block-uniform branch
        if (tid == 0) partial[tk] = 0.f;
        return;
    }

    const int b = tk / Nd;
    const int n = tk - b * Nd;
    const int t2  = n / 196;
    const int rem = n - t2 * 196;
    const int ph  = rem / 14;
    const int pw  = rem - ph * 14;

    const int i1 = tid >> 4;              // 0..15 (patch row)
    const int i2 = tid & 15;              // 0..15 (patch col)
    const int h = (ph << 4) + i1;
    const int w = (pw << 4) + i2;

    const float* fptr = outp + (size_t)tk * Dd;

    float acc = 0.f;
    #pragma unroll
    for (int i0 = 0; i0 < 2; ++i0) {
        const int t = (t2 << 1) + i0;
        // flow (map_x, map_y) for this pixel: contiguous float2, coalesced
        float2 f = *(const float2*)(fptr + (((i0 << 8) + tid) << 1));
        float mx = f.x + (float)w;
        float my = f.y + (float)h;

        float x0 = floorf(mx), y0 = floorf(my);
        float wx = mx - x0,    wy = my - y0;
        int x0i = (int)x0, y0i = (int)y0;
        int x1i = x0i + 1, y1i = y0i + 1;

        bool vx0 = (x0i >= 0) && (x0i < Wd);
        bool vx1 = (x1i >= 0) && (x1i < Wd);
        bool vy0 = (y0i >= 0) && (y0i < Hd);
        bool vy1 = (y1i >= 0) && (y1i < Hd);

        int xc0 = min(max(x0i, 0), Wd - 1);
        int xc1 = min(max(x1i, 0), Wd - 1);
        int yc0 = min(max(y0i, 0), Hd - 1);
        int yc1 = min(max(y1i, 0), Hd - 1);

        float w00 = (1.f - wx) * (1.f - wy) * ((vx0 && vy0) ? 1.f : 0.f);
        float w01 = wx         * (1.f - wy) * ((vx1 && vy0) ? 1.f : 0.f);
        float w10 = (1.f - wx) * wy         * ((vx0 && vy1) ? 1.f : 0.f);
        float w11 = wx         * wy         * ((vx1 && vy1) ? 1.f : 0.f);

        int i00 = yc0 * Wd + xc0;
        int i01 = yc0 * Wd + xc1;
        int i10 = yc1 * Wd + xc0;
        int i11 = yc1 * Wd + xc1;
        int itg = h * Wd + w;

        #pragma unroll
        for (int c = 0; c < Cd; ++c) {
            const float* img = raw + (size_t)(((b * Cd + c) * Td + t)) * HWd;
            float v00 = img[i00];
            float v01 = img[i01];
            float v10 = img[i10];
            float v11 = img[i11];
            float rec = v00 * w00 + v01 * w01 + v10 * w10 + v11 * w11;
            float tgt = img[itg];
            float d = rec - tgt;
            acc += d * d;
        }
    }

    // block reduce: 4 waves of 64
    for (int off = 32; off > 0; off >>= 1) acc += __shfl_down(acc, off, 64);
    __shared__ float sdata[4];
    int lane = tid & 63, wid = tid >> 6;
    if (lane == 0) sdata[wid] = acc;
    __syncthreads();
    if (tid == 0)
        partial[tk] = sdata[0] + sdata[1] + sdata[2] + sdata[3];
}

// ---------------- finalize: reduce partials + mask count ----------------
__global__ void finalize_kernel(const float* __restrict__ partial,
                                const int* __restrict__ mask,
                                float* __restrict__ out) {
    double s = 0.0;
    for (int i = threadIdx.x; i < MASK_N; i += blockDim.x)
        s += (double)partial[i];
    int cnt = 0;
    for (int i = threadIdx.x; i < MASK_N; i += blockDim.x)
        cnt += (mask[i] != 0) ? 1 : 0;

    for (int off = 32; off > 0; off >>= 1) {
        s   += __shfl_down(s, off, 64);
        cnt += __shfl_down(cnt, off, 64);
    }
    __shared__ double sdat[4];
    __shared__ int    cdat[4];
    int lane = threadIdx.x & 63, wid = threadIdx.x >> 6;
    if (lane == 0) { sdat[wid] = s; cdat[wid] = cnt; }
    __syncthreads();
    if (threadIdx.x == 0) {
        double st = sdat[0] + sdat[1] + sdat[2] + sdat[3];
        int ct = cdat[0] + cdat[1] + cdat[2] + cdat[3];
        double denom = (double)(ct > 0 ? ct : 1) * PATCH_ELEMS;
        out[0] = (float)(st / denom);
    }
}

extern "C" void kernel_launch(void* const* d_in, const int* in_sizes, int n_in,
                              void* d_out, int out_size, void* d_ws, size_t ws_size,
                              hipStream_t stream) {
    const float* outp = (const float*)d_in[0];   // (B,N,D) fp32
    const float* raw  = (const float*)d_in[1];   // (B,C,T,H,W) fp32
    const int*   mask = (const int*)d_in[2];     // (B,N)
    float* out = (float*)d_out;

    float* partial = (float*)d_ws;               // MASK_N floats, all written

    flow_mse_tok<<<MASK_N, 256, 0, stream>>>(outp, raw, mask, partial);
    finalize_kernel<<<1, 256, 0, stream>>>(partial, mask, out);
}

// Round 4
// 171.325 us; speedup vs baseline: 2.4911x; 1.0777x over previous
//
#include <hip/hip_runtime.h>

// Problem constants: B=8, C=3, T=16, H=W=224, P0=2, P=16, FC=2
#define Bd 8
#define Cd 3
#define Td 16
#define Hd 224
#define Wd 224
#define Nd 1568            // (T/2)*(H/16)*(W/16)
#define Dd 1024            // 2*16*16*2
#define HWd (Hd*Wd)        // 50176
#define MASK_N (Bd*Nd)     // 12544 — blocks / partials
#define PATCH_ELEMS 1536.0

#define WIN 32             // staged window: 16x16 patch + 8 halo each side
#define PITCH 40           // LDS row pitch: (8*ly + lx) % 32 -> uniform 2-way banking
#define PLANE (WIN*PITCH)  // 1280 floats per plane

// ---------------- main fused kernel: one block per token --------------------
// grid = 12544 (B*N), block = 256. Stage a 32x32 window of all 6 (c,t) planes
// into LDS with coalesced float2 loads; bilinear samples hit LDS (global
// fallback only if a sample escapes the +-8 halo, ~never for N(0,1) flows).
__global__ void flow_mse_tok(const float* __restrict__ outp,   // (B,N,D)
                             const float* __restrict__ raw,    // (B,C,T,H,W)
                             const int* __restrict__ mask,     // (B,N)
                             float* __restrict__ partial) {    // (MASK_N)
    const int tk = blockIdx.x;            // b*Nd + n
    const int tid = threadIdx.x;

    if (mask[tk] == 0) {                  // block-uniform: cheap retire
        if (tid == 0) partial[tk] = 0.f;
        return;
    }

    const int b = tk / Nd;
    const int n = tk - b * Nd;
    const int t2  = n / 196;
    const int rem = n - t2 * 196;
    const int ph  = rem / 14;
    const int pw  = rem - ph * 14;

    const int WX = min(max(pw * 16 - 8, 0), Wd - WIN);   // multiple of 8
    const int WY = min(max(ph * 16 - 8, 0), Hd - WIN);

    __shared__ float lds[6 * PLANE];      // 30720 B

    // ---- stage 6 planes: per plane each thread loads 2 float2 (rows r, r+16)
    {
        const int r  = tid >> 4;          // 0..15
        const int cc = (tid & 15) << 1;   // 0,2,...,30  (WX mult of 8 -> 8B aligned)
        #pragma unroll
        for (int p = 0; p < 6; ++p) {
            const int c  = p >> 1;
            const int i0 = p & 1;
            const int t  = (t2 << 1) + i0;
            const float* img = raw + (size_t)(((b * Cd + c) * Td + t)) * HWd;
            float2 a = *(const float2*)(img + (WY + r)      * Wd + WX + cc);
            float2 d = *(const float2*)(img + (WY + r + 16) * Wd + WX + cc);
            float* pl = lds + p * PLANE;
            pl[r * PITCH + cc]            = a.x;
            pl[r * PITCH + cc + 1]        = a.y;
            pl[(r + 16) * PITCH + cc]     = d.x;
            pl[(r + 16) * PITCH + cc + 1] = d.y;
        }
    }
    __syncthreads();

    const int i1 = tid >> 4;              // patch row
    const int i2 = tid & 15;              // patch col
    const int h = (ph << 4) + i1;
    const int w = (pw << 4) + i2;
    const int tIdx = (h - WY) * PITCH + (w - WX);   // target always in window

    const float* fptr = outp + (size_t)tk * Dd;

    float acc = 0.f;
    #pragma unroll
    for (int i0 = 0; i0 < 2; ++i0) {
        const int t = (t2 << 1) + i0;
        float2 f = *(const float2*)(fptr + (((i0 << 8) + tid) << 1));
        float mx = f.x + (float)w;
        float my = f.y + (float)h;

        float x0 = floorf(mx), y0 = floorf(my);
        float wx = mx - x0,    wy = my - y0;
        int x0i = (int)x0, y0i = (int)y0;
        int x1i = x0i + 1, y1i = y0i + 1;

        bool vx0 = (x0i >= 0) && (x0i < Wd);
        bool vx1 = (x1i >= 0) && (x1i < Wd);
        bool vy0 = (y0i >= 0) && (y0i < Hd);
        bool vy1 = (y1i >= 0) && (y1i < Hd);

        int xc0 = min(max(x0i, 0), Wd - 1);
        int xc1 = min(max(x1i, 0), Wd - 1);
        int yc0 = min(max(y0i, 0), Hd - 1);
        int yc1 = min(max(y1i, 0), Hd - 1);

        float w00 = (1.f - wx) * (1.f - wy) * ((vx0 && vy0) ? 1.f : 0.f);
        float w01 = wx         * (1.f - wy) * ((vx1 && vy0) ? 1.f : 0.f);
        float w10 = (1.f - wx) * wy         * ((vx0 && vy1) ? 1.f : 0.f);
        float w11 = wx         * wy         * ((vx1 && vy1) ? 1.f : 0.f);

        const int lx0 = xc0 - WX, lx1 = xc1 - WX;
        const int ly0 = yc0 - WY, ly1 = yc1 - WY;
        const bool ok = (lx0 >= 0) & (lx1 < WIN) & (ly0 >= 0) & (ly1 < WIN);

        if (ok) {
            const int b00 = ly0 * PITCH + lx0;
            const int b01 = ly0 * PITCH + lx1;
            const int b10 = ly1 * PITCH + lx0;
            const int b11 = ly1 * PITCH + lx1;
            #pragma unroll
            for (int c = 0; c < Cd; ++c) {
                const float* pl = lds + ((c << 1) | i0) * PLANE;
                float rec = pl[b00] * w00 + pl[b01] * w01
                          + pl[b10] * w10 + pl[b11] * w11;
                float d = rec - pl[tIdx];
                acc += d * d;
            }
        } else {                          // rare: sample escaped the halo
            const int i00 = yc0 * Wd + xc0;
            const int i01 = yc0 * Wd + xc1;
            const int i10 = yc1 * Wd + xc0;
            const int i11 = yc1 * Wd + xc1;
            #pragma unroll
            for (int c = 0; c < Cd; ++c) {
                const float* img = raw + (size_t)(((b * Cd + c) * Td + t)) * HWd;
                float rec = img[i00] * w00 + img[i01] * w01
                          + img[i10] * w10 + img[i11] * w11;
                const float* pl = lds + ((c << 1) | i0) * PLANE;
                float d = rec - pl[tIdx];
                acc += d * d;
            }
        }
    }

    // block reduce: 4 waves of 64
    for (int off = 32; off > 0; off >>= 1) acc += __shfl_down(acc, off, 64);
    __shared__ float sdata[4];
    int lane = tid & 63, wid = tid >> 6;
    if (lane == 0) sdata[wid] = acc;
    __syncthreads();
    if (tid == 0)
        partial[tk] = sdata[0] + sdata[1] + sdata[2] + sdata[3];
}

// ---------------- finalize: reduce partials + mask count ----------------
__global__ void finalize_kernel(const float* __restrict__ partial,
                                const int* __restrict__ mask,
                                float* __restrict__ out) {
    double s = 0.0;
    int cnt = 0;
    for (int i = threadIdx.x; i < MASK_N; i += blockDim.x) {
        s   += (double)partial[i];
        cnt += (mask[i] != 0) ? 1 : 0;
    }
    for (int off = 32; off > 0; off >>= 1) {
        s   += __shfl_down(s, off, 64);
        cnt += __shfl_down(cnt, off, 64);
    }
    __shared__ double sdat[4];
    __shared__ int    cdat[4];
    int lane = threadIdx.x & 63, wid = threadIdx.x >> 6;
    if (lane == 0) { sdat[wid] = s; cdat[wid] = cnt; }
    __syncthreads();
    if (threadIdx.x == 0) {
        double st = sdat[0] + sdat[1] + sdat[2] + sdat[3];
        int ct = cdat[0] + cdat[1] + cdat[2] + cdat[3];
        double denom = (double)(ct > 0 ? ct : 1) * PATCH_ELEMS;
        out[0] = (float)(st / denom);
    }
}

extern "C" void kernel_launch(void* const* d_in, const int* in_sizes, int n_in,
                              void* d_out, int out_size, void* d_ws, size_t ws_size,
                              hipStream_t stream) {
    const float* outp = (const float*)d_in[0];   // (B,N,D) fp32
    const float* raw  = (const float*)d_in[1];   // (B,C,T,H,W) fp32
    const int*   mask = (const int*)d_in[2];     // (B,N)
    float* out = (float*)d_out;

    float* partial = (float*)d_ws;               // MASK_N floats, all written

    flow_mse_tok<<<MASK_N, 256, 0, stream>>>(outp, raw, mask, partial);
    finalize_kernel<<<1, 256, 0, stream>>>(partial, mask, out);
}